// Round 5
// baseline (129.808 us; speedup 1.0000x reference)
//
#include <hip/hip_runtime.h>
#include <hip/hip_bf16.h>

typedef short bf16x8 __attribute__((ext_vector_type(8)));
typedef float f32x4 __attribute__((ext_vector_type(4)));

#define T_LEN 512
#define BATCH 32
#define D 512
#define M_TOT (T_LEN * BATCH) /* 16384 */
#define NLAYER 4

#define BM 256
#define BN 128
#define BK 64
#define NT (D / BK)     /* 8 K-tiles */
#define TILE_ELEMS (BM * BK + BN * BK) /* 24576 elems = 48KB per ring slot */
#define SMEM_BYTES (3 * TILE_ELEMS * 2) /* 144KB */
#define EP 72 /* epilogue LDS row stride */

#define CH 32            /* scan chunk length */
#define NCH (T_LEN / CH) /* 16 chunks */

#define SBAR()                                  \
    do {                                        \
        __builtin_amdgcn_s_barrier();           \
        __builtin_amdgcn_sched_barrier(0);      \
    } while (0)
#define VMCNT6()                                             \
    do {                                                     \
        asm volatile("s_waitcnt vmcnt(6)" ::: "memory");     \
        __builtin_amdgcn_sched_barrier(0);                   \
    } while (0)
#define VMCNT0()                                             \
    do {                                                     \
        asm volatile("s_waitcnt vmcnt(0)" ::: "memory");     \
        __builtin_amdgcn_sched_barrier(0);                   \
    } while (0)

// ---------------- fp32 -> bf16 convert (W and x in one launch) ----------------
__global__ __launch_bounds__(256) void convert_k(const float* __restrict__ W,
                                                 const float* __restrict__ x,
                                                 __hip_bfloat16* __restrict__ Wb,
                                                 __hip_bfloat16* __restrict__ xb) {
    const int nW = NLAYER * D * D; // 1048576
    const int nX = M_TOT * D;      // 8388608
    int i = (blockIdx.x * 256 + threadIdx.x) * 4;
    const float* src;
    __hip_bfloat16* dst;
    if (i < nW) {
        src = W + i;
        dst = Wb + i;
    } else {
        int k = i - nW;
        if (k >= nX) return;
        src = x + k;
        dst = xb + k;
    }
    float4 v = *(const float4*)src;
    __hip_bfloat16 h0 = __float2bfloat16(v.x);
    __hip_bfloat16 h1 = __float2bfloat16(v.y);
    __hip_bfloat16 h2 = __float2bfloat16(v.z);
    __hip_bfloat16 h3 = __float2bfloat16(v.w);
    ushort4 o;
    o.x = *(const unsigned short*)&h0;
    o.y = *(const unsigned short*)&h1;
    o.z = *(const unsigned short*)&h2;
    o.w = *(const unsigned short*)&h3;
    *(ushort4*)dst = o;
}

// ---------------- bf16 GEMM: Cb[M][N] = bf16(A[M][K] * Bt[N][K]^T + bias) -----
// 256x128 tile, 8 waves (4M x 2N, each 64x64), BK=64, ring-3 LDS (144KB dyn),
// counted vmcnt(6) across raw s_barriers (no drain until last tile),
// chunk-XOR swizzle (pre-swizzled global source, linear LDS dest, swizzled
// read), XCD-aware block swizzle, setprio around MFMA, LDS-staged epilogue.
//
// Per-wave per K-tile: 6 global_load_lds (4 A + 2 B) -> vmcnt(6) == exactly
// one full tile in flight. Ring-3 ensures stage(t+2)'s destination was last
// read at C(t-1), which every wave finished >=1 barrier ago: no race.
__global__ __launch_bounds__(512, 2) void gemm_bt(const __hip_bfloat16* __restrict__ A,
                                                  const __hip_bfloat16* __restrict__ Bt,
                                                  const float* __restrict__ bias,
                                                  __hip_bfloat16* __restrict__ Cb) {
    constexpr int K = D;
    constexpr int N = D;
    extern __shared__ __hip_bfloat16 smem[];

    const int tid  = threadIdx.x;
    const int wave = tid >> 6;
    const int lane = tid & 63;

    // XCD swizzle: 256 blocks = 8 XCDs x (8 bm x 4 bn); A-panel reused 4x in L2.
    const int bid = blockIdx.x;
    const int xcd = bid & 7;
    const int j   = bid >> 3;            // 0..31
    const int bm  = xcd * 8 + (j >> 2);  // 0..63
    const int bn  = j & 3;               // 0..3

    const int wm3 = wave >> 1; // 0..3 -> A row block of 64
    const int wn1 = wave & 1;  // 0..1 -> B row block of 64

    // staging lane map: row = lane>>3 (0..7), chunk = lane&7, source pre-XORed
    const int srow = lane >> 3;
    const int scol = ((lane & 7) ^ srow) * 8;

    const __hip_bfloat16* Ag = A  + (size_t)(bm * BM) * K;
    const __hip_bfloat16* Bg = Bt + (size_t)(bn * BN) * K;

    f32x4 acc[4][4] = {};

#define STAGE(slot, k0)                                                                              \
    do {                                                                                             \
        __hip_bfloat16* const Asl = smem + (slot) * TILE_ELEMS;                                      \
        __hip_bfloat16* const Bsl = Asl + BM * BK;                                                   \
        _Pragma("unroll") for (int jj = 0; jj < 4; ++jj) {                                           \
            const int rbase = (wave * 4 + jj) * 8;                                                   \
            __builtin_amdgcn_global_load_lds(                                                        \
                (const __attribute__((address_space(1))) void*)(Ag + (size_t)(rbase + srow) * K + (k0) + scol), \
                (__attribute__((address_space(3))) void*)(Asl + rbase * BK), 16, 0, 0);              \
        }                                                                                            \
        _Pragma("unroll") for (int jj = 0; jj < 2; ++jj) {                                           \
            const int rbase = (wave * 2 + jj) * 8;                                                   \
            __builtin_amdgcn_global_load_lds(                                                        \
                (const __attribute__((address_space(1))) void*)(Bg + (size_t)(rbase + srow) * K + (k0) + scol), \
                (__attribute__((address_space(3))) void*)(Bsl + rbase * BK), 16, 0, 0);              \
        }                                                                                            \
    } while (0)

#define COMPUTE(slot)                                                                                \
    do {                                                                                             \
        const __hip_bfloat16* const Asl = smem + (slot) * TILE_ELEMS;                                \
        const __hip_bfloat16* const Bsl = Asl + BM * BK;                                             \
        bf16x8 af[4][2], bv[4][2];                                                                   \
        const int fr = lane & 15;                                                                    \
        const int kq = lane >> 4;                                                                    \
        _Pragma("unroll") for (int mi = 0; mi < 4; ++mi) {                                           \
            const int r = wm3 * 64 + mi * 16 + fr;                                                   \
            _Pragma("unroll") for (int kh = 0; kh < 2; ++kh) {                                       \
                const int c = ((kh * 4 + kq) ^ (fr & 7)) * 8;                                        \
                af[mi][kh] = *(const bf16x8*)(&Asl[r * BK + c]);                                     \
            }                                                                                        \
        }                                                                                            \
        _Pragma("unroll") for (int ni = 0; ni < 4; ++ni) {                                           \
            const int r = wn1 * 64 + ni * 16 + fr;                                                   \
            _Pragma("unroll") for (int kh = 0; kh < 2; ++kh) {                                       \
                const int c = ((kh * 4 + kq) ^ (fr & 7)) * 8;                                        \
                bv[ni][kh] = *(const bf16x8*)(&Bsl[r * BK + c]);                                     \
            }                                                                                        \
        }                                                                                            \
        __builtin_amdgcn_s_setprio(1);                                                               \
        _Pragma("unroll") for (int kh = 0; kh < 2; ++kh)                                             \
            _Pragma("unroll") for (int mi = 0; mi < 4; ++mi)                                         \
                _Pragma("unroll") for (int ni = 0; ni < 4; ++ni)                                     \
                    acc[mi][ni] = __builtin_amdgcn_mfma_f32_16x16x32_bf16(af[mi][kh], bv[ni][kh],    \
                                                                          acc[mi][ni], 0, 0, 0);    \
        __builtin_amdgcn_s_setprio(0);                                                               \
    } while (0)

    // prologue: tiles 0,1 staged; own T0 complete; barrier -> all waves' T0 done
    STAGE(0, 0);
    STAGE(1, BK);
    VMCNT6();
    SBAR();

#pragma unroll
    for (int t = 0; t < NT; ++t) {
        COMPUTE(t % 3); // T(t) guaranteed complete block-wide (prev iter's vmcnt+barrier)
        if (t < NT - 1) {
            SBAR(); // all waves done reading; frees ring slot (t+2)%3
            if (t + 2 < NT) STAGE((t + 2) % 3, (t + 2) * BK);
            if (t < NT - 2) {
                VMCNT6(); // own T(t+1) contributions complete; T(t+2) stays in flight
            } else {
                VMCNT0(); // tail: drain T(NT-1)
            }
            SBAR(); // all waves' T(t+1) complete -> next COMPUTE safe
        }
    }
    SBAR(); // epilogue reuses LDS

    // ---- epilogue: stage wave's 64x64 tile in LDS, store coalesced rows ----
    // C/D layout: col=lane&15, row=(lane>>4)*4 + r  [m89-verified]
    {
        __hip_bfloat16* S = smem + wave * (64 * EP);
        const int cfr = lane & 15;
        const int cfq = lane >> 4;
        float bs[4];
#pragma unroll
        for (int ni = 0; ni < 4; ++ni) bs[ni] = bias[bn * BN + wn1 * 64 + ni * 16 + cfr];
#pragma unroll
        for (int mi = 0; mi < 4; ++mi)
#pragma unroll
            for (int ni = 0; ni < 4; ++ni)
#pragma unroll
                for (int r = 0; r < 4; ++r)
                    S[(mi * 16 + cfq * 4 + r) * EP + ni * 16 + cfr] =
                        __float2bfloat16(acc[mi][ni][r] + bs[ni]);
        // wave-local read-back (lgkmcnt deps keep ordering within the wave)
        const int rq = lane >> 3;      // 0..7
        const int cl = (lane & 7) * 8; // 0..56
#pragma unroll
        for (int p = 0; p < 8; ++p) {
            const int lr = p * 8 + rq;
            bf16x8 v = *(const bf16x8*)(S + lr * EP + cl);
            *(bf16x8*)(&Cb[(size_t)(bm * BM + wm3 * 64 + lr) * N + bn * BN + wn1 * 64 + cl]) = v;
        }
    }
#undef STAGE
#undef COMPUTE
}

// ---------------- fused parallel scan: h_t = max(0, a_t + u*h_{t-1}) ---------
// Chunk decomposition (h>=0 domain): F_c(h) = max(m, d + e*h), e = u^CH.
// Block = 16 chunks x 32 lanes x 2 channels (512 thr, 256 blocks). Each thread
// keeps its chunk's 32 t-steps x 2 channels in registers (u32 loads), exchanges
// (m,d) via LDS, combines, replays. Xh read ONCE, u32/float2 stores.
template <int MODE>
__global__ __launch_bounds__(512) void scan_k(const __hip_bfloat16* __restrict__ xh,
                                              const float* __restrict__ u,
                                              float* __restrict__ outf,
                                              __hip_bfloat16* __restrict__ outb) {
    __shared__ float4 md[NCH][32];
    const int i2  = threadIdx.x & 31;
    const int c   = threadIdx.x >> 5; // 0..15
    const int idx = blockIdx.x * 64 + i2 * 2;
    const float u0 = u[idx & (D - 1)];
    const float u1 = u[(idx + 1) & (D - 1)];

    const __hip_bfloat16* p = xh + (size_t)c * CH * M_TOT + idx;
    unsigned int xv[CH];
#pragma unroll
    for (int t = 0; t < CH; ++t) xv[t] = *(const unsigned int*)(p + (size_t)t * M_TOT);

    float m0 = 0.f, d0 = 0.f, m1 = 0.f, d1 = 0.f;
#pragma unroll
    for (int t = 0; t < CH; ++t) {
        const float a0 = __uint_as_float(xv[t] << 16);
        const float a1 = __uint_as_float(xv[t] & 0xffff0000u);
        m0 = fmaxf(fmaf(u0, m0, a0), 0.f);
        d0 = fmaf(u0, d0, a0);
        m1 = fmaxf(fmaf(u1, m1, a1), 0.f);
        d1 = fmaf(u1, d1, a1);
    }
    md[c][i2] = make_float4(m0, d0, m1, d1);
    __syncthreads();

    float e0 = u0 * u0, e1 = u1 * u1;            // u^2
    e0 *= e0; e0 *= e0; e0 *= e0; e0 *= e0;      // u^32 == u^CH
    e1 *= e1; e1 *= e1; e1 *= e1; e1 *= e1;
    float h0 = 0.f, h1 = 0.f;
    for (int jj = 0; jj < c; ++jj) {
        const float4 v = md[jj][i2];
        h0 = fmaxf(v.x, fmaf(e0, h0, v.y));
        h1 = fmaxf(v.z, fmaf(e1, h1, v.w));
    }

    const size_t base = (size_t)c * CH * M_TOT + idx;
#pragma unroll
    for (int t = 0; t < CH; ++t) {
        const size_t off = base + (size_t)t * M_TOT;
        const float a0 = __uint_as_float(xv[t] << 16);
        const float a1 = __uint_as_float(xv[t] & 0xffff0000u);
        h0 = fmaxf(fmaf(u0, h0, a0), 0.f);
        h1 = fmaxf(fmaf(u1, h1, a1), 0.f);
        if (MODE & 1) *(float2*)(outf + off) = make_float2(h0, h1);
        if (MODE & 2) {
            __hip_bfloat16 b0 = __float2bfloat16(h0);
            __hip_bfloat16 b1 = __float2bfloat16(h1);
            unsigned int pk = (unsigned int)(*(unsigned short*)&b0) |
                              ((unsigned int)(*(unsigned short*)&b1) << 16);
            *(unsigned int*)(outb + off) = pk;
        }
    }
}

extern "C" void kernel_launch(void* const* d_in, const int* in_sizes, int n_in,
                              void* d_out, int out_size, void* d_ws, size_t ws_size,
                              hipStream_t stream) {
    const float* x = (const float*)d_in[0]; // [T, B, Din]
    const float* W = (const float*)d_in[1]; // [L, Dh, Din]
    const float* b = (const float*)d_in[2]; // [L, Dh]
    const float* u = (const float*)d_in[3]; // [L, Dh]
    float* out = (float*)d_out;             // [T, B, Dh]

    __hip_bfloat16* Wb = (__hip_bfloat16*)d_ws;                                       // 2 MB
    __hip_bfloat16* Ab = (__hip_bfloat16*)((char*)d_ws + (size_t)NLAYER * D * D * 2); // 16.8 MB
    __hip_bfloat16* Xh = Ab + (size_t)M_TOT * D;                                      // 16.8 MB

    // allow 144KB dynamic LDS (idempotent; not a stream op, graph-capture safe)
    (void)hipFuncSetAttribute((const void*)gemm_bt,
                              hipFuncAttributeMaxDynamicSharedMemorySize, SMEM_BYTES);

    const int n_conv = NLAYER * D * D + M_TOT * D;
    convert_k<<<n_conv / 4 / 256, 256, 0, stream>>>(W, x, Wb, Ab);

    for (int l = 0; l < NLAYER; ++l) {
        gemm_bt<<<(M_TOT / BM) * (D / BN), 512, SMEM_BYTES, stream>>>(
            Ab, Wb + (size_t)l * D * D, b + (size_t)l * D, Xh);
        if (l < NLAYER - 1) {
            scan_k<2><<<M_TOT / 64, 512, 0, stream>>>(Xh, u + (size_t)l * D, nullptr, Ab);
        } else {
            scan_k<1><<<M_TOT / 64, 512, 0, stream>>>(Xh, u + (size_t)l * D, out, nullptr);
        }
    }
}

// Round 7
// 116.297 us; speedup vs baseline: 1.1162x; 1.1162x over previous
//
#include <hip/hip_runtime.h>
#include <hip/hip_bf16.h>

typedef short bf16x8 __attribute__((ext_vector_type(8)));
typedef float f32x4 __attribute__((ext_vector_type(4)));

#define T_LEN 512
#define BATCH 32
#define D 512
#define M_TOT (T_LEN * BATCH) /* 16384 */
#define NLAYER 4

#define BM 128
#define BN 128
#define BK 64
#define NT (D / BK) /* 8 K-tiles */
#define EP 72       /* epilogue LDS row stride (144B, 16B-aligned, conflict-free b128 read) */

#define CH 32            /* scan chunk length */
#define NCH (T_LEN / CH) /* 16 chunks */

// ---------------- fp32 -> bf16 convert (W only; x is fused into GEMM0) -------
__global__ __launch_bounds__(256) void convert_k(const float* __restrict__ W,
                                                 __hip_bfloat16* __restrict__ Wb) {
    const int i = (blockIdx.x * 256 + threadIdx.x) * 4; // n = 1048576, exact
    float4 v = *(const float4*)(W + i);
    __hip_bfloat16 h0 = __float2bfloat16(v.x);
    __hip_bfloat16 h1 = __float2bfloat16(v.y);
    __hip_bfloat16 h2 = __float2bfloat16(v.z);
    __hip_bfloat16 h3 = __float2bfloat16(v.w);
    ushort4 o;
    o.x = *(const unsigned short*)&h0;
    o.y = *(const unsigned short*)&h1;
    o.z = *(const unsigned short*)&h2;
    o.w = *(const unsigned short*)&h3;
    *(ushort4*)(Wb + i) = o;
}

// ---------------- bf16 GEMM: Cb[M][N] = bf16(A[M][K] * Bt[N][K]^T + bias) -----
// 128x128 tile, 4 waves (2x2), 16x16x32 MFMA, BK=64, 2-phase double-buffer,
// chunk-XOR swizzle (both-sides), XCD-aware block swizzle, LDS-staged epilogue.
// AF32: A is fp32 (layer 0 = raw x) -> reg-staged with in-reg bf16 convert,
//       T14 split: loads issued BEFORE compute, vmcnt+ds_write after.
// else: A is bf16 -> global_load_lds fast path (proven round-4 structure).
template <bool AF32>
__global__ __launch_bounds__(256) void gemm_bt(const void* __restrict__ Avp,
                                               const __hip_bfloat16* __restrict__ Bt,
                                               const float* __restrict__ bias,
                                               __hip_bfloat16* __restrict__ Cb) {
    constexpr int K = D;
    constexpr int N = D;
    __shared__ __hip_bfloat16 smem[4 * BM * BK]; // 64KB
    __hip_bfloat16* const AsP[2] = {smem, smem + BM * BK};
    __hip_bfloat16* const BsP[2] = {smem + 2 * BM * BK, smem + 3 * BM * BK};

    const int tid  = threadIdx.x;
    const int wave = tid >> 6;
    const int lane = tid & 63;

    // XCD swizzle: 512 blocks = 8 XCDs x 64; the 4 bn-tiles of one bm stay on
    // one XCD so the A-panel is fetched into that XCD's L2 once.
    const int bid = blockIdx.x;
    const int xcd = bid & 7;
    const int jb  = bid >> 3;
    const int bm  = xcd * 16 + (jb >> 2); // 0..127
    const int bn  = jb & 3;               // 0..3

    const int wm = (wave >> 1) * 64;
    const int wn = (wave & 1) * 64;

    // staging lane map: row = lane>>3 (0..7), chunk = lane&7, source pre-XORed.
    // LDS(row, cp) holds global chunk cp ^ (row&7); read side applies same XOR.
    const int srow = lane >> 3;
    const int scol = ((lane & 7) ^ srow) * 8; // element offset of source chunk

    const __hip_bfloat16* Ag = AF32 ? nullptr
                                    : (const __hip_bfloat16*)Avp + (size_t)(bm * BM) * K;
    const float* Agf = AF32 ? (const float*)Avp + (size_t)(bm * BM) * K : nullptr;
    const __hip_bfloat16* Bg = Bt + (size_t)(bn * BN) * K;

    f32x4 acc[4][4] = {};
    float4 va[4][2]; // AF32 in-flight A registers (static indexing only)

#define STAGE_A_LDS(buf, k0)                                                                         \
    do {                                                                                             \
        _Pragma("unroll") for (int jj = 0; jj < 4; ++jj) {                                           \
            const int rbase = (jj * 4 + wave) * 8;                                                   \
            __builtin_amdgcn_global_load_lds(                                                        \
                (const __attribute__((address_space(1))) void*)(Ag + (size_t)(rbase + srow) * K + (k0) + scol), \
                (__attribute__((address_space(3))) void*)(&AsP[buf][rbase * BK]), 16, 0, 0);         \
        }                                                                                            \
    } while (0)

#define STAGE_B(buf, k0)                                                                             \
    do {                                                                                             \
        _Pragma("unroll") for (int jj = 0; jj < 4; ++jj) {                                           \
            const int rbase = (jj * 4 + wave) * 8;                                                   \
            __builtin_amdgcn_global_load_lds(                                                        \
                (const __attribute__((address_space(1))) void*)(Bg + (size_t)(rbase + srow) * K + (k0) + scol), \
                (__attribute__((address_space(3))) void*)(&BsP[buf][rbase * BK]), 16, 0, 0);         \
        }                                                                                            \
    } while (0)

// issue A fp32 loads (no wait) — 8 x global_load_dwordx4 per wave
#define LOAD_A_F32(k0)                                                                               \
    do {                                                                                             \
        _Pragma("unroll") for (int jj = 0; jj < 4; ++jj) {                                           \
            const int rbase = (jj * 4 + wave) * 8;                                                   \
            const float* s = Agf + (size_t)(rbase + srow) * K + (k0) + scol;                         \
            va[jj][0] = *(const float4*)s;                                                           \
            va[jj][1] = *(const float4*)(s + 4);                                                     \
        }                                                                                            \
    } while (0)

// convert + ds_write to the linear dest gload_lds would have used
#define WRITE_A_F32(buf)                                                                             \
    do {                                                                                             \
        _Pragma("unroll") for (int jj = 0; jj < 4; ++jj) {                                           \
            const int rbase = (jj * 4 + wave) * 8;                                                   \
            bf16x8 pk;                                                                               \
            _Pragma("unroll") for (int q = 0; q < 4; ++q) {                                          \
                __hip_bfloat16 t0 = __float2bfloat16(((const float*)&va[jj][0])[q]);                 \
                __hip_bfloat16 t1 = __float2bfloat16(((const float*)&va[jj][1])[q]);                 \
                pk[q]     = *(const short*)&t0;                                                      \
                pk[q + 4] = *(const short*)&t1;                                                      \
            }                                                                                        \
            *(bf16x8*)(&AsP[buf][(rbase + srow) * BK + (lane & 7) * 8]) = pk;                        \
        }                                                                                            \
    } while (0)

#define COMPUTE(buf)                                                                                 \
    do {                                                                                             \
        bf16x8 af[4][2], bv[4][2];                                                                   \
        const int fr = lane & 15;                                                                    \
        const int kq = lane >> 4;                                                                    \
        _Pragma("unroll") for (int mi = 0; mi < 4; ++mi) {                                           \
            const int r = wm + mi * 16 + fr;                                                         \
            _Pragma("unroll") for (int kh = 0; kh < 2; ++kh) {                                       \
                const int c = ((kh * 4 + kq) ^ (fr & 7)) * 8;                                        \
                af[mi][kh] = *(const bf16x8*)(&AsP[buf][r * BK + c]);                                \
            }                                                                                        \
        }                                                                                            \
        _Pragma("unroll") for (int ni = 0; ni < 4; ++ni) {                                           \
            const int r = wn + ni * 16 + fr;                                                         \
            _Pragma("unroll") for (int kh = 0; kh < 2; ++kh) {                                       \
                const int c = ((kh * 4 + kq) ^ (fr & 7)) * 8;                                        \
                bv[ni][kh] = *(const bf16x8*)(&BsP[buf][r * BK + c]);                                \
            }                                                                                        \
        }                                                                                            \
        _Pragma("unroll") for (int kh = 0; kh < 2; ++kh)                                             \
            _Pragma("unroll") for (int mi = 0; mi < 4; ++mi)                                         \
                _Pragma("unroll") for (int ni = 0; ni < 4; ++ni)                                     \
                    acc[mi][ni] = __builtin_amdgcn_mfma_f32_16x16x32_bf16(af[mi][kh], bv[ni][kh],    \
                                                                          acc[mi][ni], 0, 0, 0);    \
    } while (0)

    if constexpr (AF32) {
        // prologue
        LOAD_A_F32(0);
        STAGE_B(0, 0);     // B loads fly while we wait on va
        WRITE_A_F32(0);
        __syncthreads();
        int cur = 0;
#pragma unroll
        for (int kt = 1; kt < NT; ++kt) {
            LOAD_A_F32(kt * BK);     // issue early (T14)
            STAGE_B(cur ^ 1, kt * BK);
            COMPUTE(cur);            // hide global latency under MFMA
            WRITE_A_F32(cur ^ 1);    // vmcnt lands here, after compute
            __syncthreads();
            cur ^= 1;
        }
        COMPUTE(cur);
    } else {
        STAGE_A_LDS(0, 0);
        STAGE_B(0, 0);
        __syncthreads();
        int cur = 0;
#pragma unroll
        for (int kt = 1; kt < NT; ++kt) {
            STAGE_A_LDS(cur ^ 1, kt * BK);
            STAGE_B(cur ^ 1, kt * BK);
            COMPUTE(cur);
            __syncthreads();
            cur ^= 1;
        }
        COMPUTE(cur);
    }
    __syncthreads(); // all waves done with As/Bs before LDS reuse

    // ---- epilogue: stage wave's 64x64 tile in LDS, store coalesced rows ----
    // C/D layout: col=lane&15, row=(lane>>4)*4 + r  [m89-verified]
    {
        __hip_bfloat16* S = smem + wave * (64 * EP);
        const int cfr = lane & 15;
        const int cfq = lane >> 4;
        float bs[4];
#pragma unroll
        for (int ni = 0; ni < 4; ++ni) bs[ni] = bias[bn * BN + wn + ni * 16 + cfr];
#pragma unroll
        for (int mi = 0; mi < 4; ++mi)
#pragma unroll
            for (int ni = 0; ni < 4; ++ni)
#pragma unroll
                for (int r = 0; r < 4; ++r)
                    S[(mi * 16 + cfq * 4 + r) * EP + ni * 16 + cfr] =
                        __float2bfloat16(acc[mi][ni][r] + bs[ni]);
        // wave-local read-back (lgkmcnt deps keep ordering within the wave)
        const int rq = lane >> 3;      // 0..7
        const int cl = (lane & 7) * 8; // 0..56
#pragma unroll
        for (int p = 0; p < 8; ++p) {
            const int lr = p * 8 + rq;
            bf16x8 v = *(const bf16x8*)(S + lr * EP + cl);
            *(bf16x8*)(&Cb[(size_t)(bm * BM + wm + lr) * N + bn * BN + wn + cl]) = v;
        }
    }
#undef STAGE_A_LDS
#undef STAGE_B
#undef LOAD_A_F32
#undef WRITE_A_F32
#undef COMPUTE
}

// ---------------- fused parallel scan: h_t = max(0, a_t + u*h_{t-1}) ---------
// Chunk decomposition (h>=0 domain): F_c(h) = max(m, d + e*h), e = u^CH.
// Block = 16 chunks x 32 lanes x 2 channels (512 thr, 256 blocks). Each thread
// keeps its chunk's 32 t-steps x 2 channels in registers (u32 loads), exchanges
// (m,d) via LDS, combines, replays. Xh read ONCE.
template <int MODE>
__global__ __launch_bounds__(512) void scan_k(const __hip_bfloat16* __restrict__ xh,
                                              const float* __restrict__ u,
                                              float* __restrict__ outf,
                                              __hip_bfloat16* __restrict__ outb) {
    __shared__ float4 md[NCH][32];
    const int i2  = threadIdx.x & 31;
    const int c   = threadIdx.x >> 5; // 0..15
    const int idx = blockIdx.x * 64 + i2 * 2;
    const float u0 = u[idx & (D - 1)];
    const float u1 = u[(idx + 1) & (D - 1)];

    const __hip_bfloat16* p = xh + (size_t)c * CH * M_TOT + idx;
    unsigned int xv[CH];
#pragma unroll
    for (int t = 0; t < CH; ++t) xv[t] = *(const unsigned int*)(p + (size_t)t * M_TOT);

    float m0 = 0.f, d0 = 0.f, m1 = 0.f, d1 = 0.f;
#pragma unroll
    for (int t = 0; t < CH; ++t) {
        const float a0 = __uint_as_float(xv[t] << 16);
        const float a1 = __uint_as_float(xv[t] & 0xffff0000u);
        m0 = fmaxf(fmaf(u0, m0, a0), 0.f);
        d0 = fmaf(u0, d0, a0);
        m1 = fmaxf(fmaf(u1, m1, a1), 0.f);
        d1 = fmaf(u1, d1, a1);
    }
    md[c][i2] = make_float4(m0, d0, m1, d1);
    __syncthreads();

    float e0 = u0 * u0, e1 = u1 * u1;       // u^2
    e0 *= e0; e0 *= e0; e0 *= e0; e0 *= e0; // u^32 == u^CH
    e1 *= e1; e1 *= e1; e1 *= e1; e1 *= e1;
    float h0 = 0.f, h1 = 0.f;
    for (int jj = 0; jj < c; ++jj) {
        const float4 v = md[jj][i2];
        h0 = fmaxf(v.x, fmaf(e0, h0, v.y));
        h1 = fmaxf(v.z, fmaf(e1, h1, v.w));
    }

    const size_t base = (size_t)c * CH * M_TOT + idx;
#pragma unroll
    for (int t = 0; t < CH; ++t) {
        const size_t off = base + (size_t)t * M_TOT;
        const float a0 = __uint_as_float(xv[t] << 16);
        const float a1 = __uint_as_float(xv[t] & 0xffff0000u);
        h0 = fmaxf(fmaf(u0, h0, a0), 0.f);
        h1 = fmaxf(fmaf(u1, h1, a1), 0.f);
        if (MODE & 1) *(float2*)(outf + off) = make_float2(h0, h1);
        if (MODE & 2) {
            __hip_bfloat16 b0 = __float2bfloat16(h0);
            __hip_bfloat16 b1 = __float2bfloat16(h1);
            unsigned int pk = (unsigned int)(*(unsigned short*)&b0) |
                              ((unsigned int)(*(unsigned short*)&b1) << 16);
            *(unsigned int*)(outb + off) = pk;
        }
    }
}

extern "C" void kernel_launch(void* const* d_in, const int* in_sizes, int n_in,
                              void* d_out, int out_size, void* d_ws, size_t ws_size,
                              hipStream_t stream) {
    const float* x = (const float*)d_in[0]; // [T, B, Din]
    const float* W = (const float*)d_in[1]; // [L, Dh, Din]
    const float* b = (const float*)d_in[2]; // [L, Dh]
    const float* u = (const float*)d_in[3]; // [L, Dh]
    float* out = (float*)d_out;             // [T, B, Dh]

    __hip_bfloat16* Wb = (__hip_bfloat16*)d_ws;                                       // 2 MB
    __hip_bfloat16* Ab = (__hip_bfloat16*)((char*)d_ws + (size_t)NLAYER * D * D * 2); // 16.8 MB
    __hip_bfloat16* Xh = Ab + (size_t)M_TOT * D;                                      // 16.8 MB

    convert_k<<<(NLAYER * D * D / 4) / 256, 256, 0, stream>>>(W, Wb);

    for (int l = 0; l < NLAYER; ++l) {
        if (l == 0) {
            gemm_bt<true><<<(M_TOT / BM) * (D / BN), 256, 0, stream>>>(
                (const void*)x, Wb, b, Xh);
        } else {
            gemm_bt<false><<<(M_TOT / BM) * (D / BN), 256, 0, stream>>>(
                (const void*)Ab, Wb + (size_t)l * D * D, b + (size_t)l * D, Xh);
        }
        if (l < NLAYER - 1) {
            scan_k<2><<<M_TOT / 64, 512, 0, stream>>>(Xh, u + (size_t)l * D, nullptr, Ab);
        } else {
            scan_k<1><<<M_TOT / 64, 512, 0, stream>>>(Xh, u + (size_t)l * D, out, nullptr);
        }
    }
}

// Round 8
// 116.217 us; speedup vs baseline: 1.1169x; 1.0007x over previous
//
#include <hip/hip_runtime.h>
#include <hip/hip_bf16.h>

typedef short bf16x8 __attribute__((ext_vector_type(8)));
typedef float f32x4 __attribute__((ext_vector_type(4)));

#define T_LEN 512
#define BATCH 32
#define D 512
#define M_TOT (T_LEN * BATCH) /* 16384 */
#define NLAYER 4

/* ---- layer-0 GEMM (fp32 A, proven round-7 structure) ---- */
#define BM 128
#define BN 128
#define BK 64
#define NT (D / BK) /* 8 K-tiles */
#define EP 72

/* ---- ring-3 GEMM (layers 1-3) ---- */
#define RBM 128
#define RBN 64
#define RSLOT (RBM * BK + RBN * BK)       /* 12288 elems = 24KB */
#define RSMEM_BYTES (3 * RSLOT * 2)       /* 72KB dynamic */
#define REP 40                            /* epilogue stride for 32-col tiles */

#define CH 32            /* scan chunk length */
#define NCH (T_LEN / CH) /* 16 chunks */

#define SBAR()                             \
    do {                                   \
        __builtin_amdgcn_s_barrier();      \
        __builtin_amdgcn_sched_barrier(0); \
    } while (0)
#define VMCNT(n)                                                   \
    do {                                                           \
        asm volatile("s_waitcnt vmcnt(" #n ")" ::: "memory");      \
        __builtin_amdgcn_sched_barrier(0);                         \
    } while (0)

// ---------------- fp32 -> bf16 convert (W only) ----------------
__global__ __launch_bounds__(256) void convert_k(const float* __restrict__ W,
                                                 __hip_bfloat16* __restrict__ Wb) {
    const int i = (blockIdx.x * 256 + threadIdx.x) * 4; // n = 1048576, exact
    float4 v = *(const float4*)(W + i);
    __hip_bfloat16 h0 = __float2bfloat16(v.x);
    __hip_bfloat16 h1 = __float2bfloat16(v.y);
    __hip_bfloat16 h2 = __float2bfloat16(v.z);
    __hip_bfloat16 h3 = __float2bfloat16(v.w);
    ushort4 o;
    o.x = *(const unsigned short*)&h0;
    o.y = *(const unsigned short*)&h1;
    o.z = *(const unsigned short*)&h2;
    o.w = *(const unsigned short*)&h3;
    *(ushort4*)(Wb + i) = o;
}

// ---------------- layer-0 GEMM: A fp32 (raw x), reg-staged convert ----------
// 128x128 tile, 4 waves, 2-phase dbuf, chunk-XOR swizzle, XCD swizzle,
// LDS-staged coalesced epilogue. Proven round-7 structure.
__global__ __launch_bounds__(256) void gemm_l0(const float* __restrict__ Agf0,
                                               const __hip_bfloat16* __restrict__ Bt,
                                               const float* __restrict__ bias,
                                               __hip_bfloat16* __restrict__ Cb) {
    constexpr int K = D;
    constexpr int N = D;
    __shared__ __hip_bfloat16 smem[4 * BM * BK]; // 64KB
    __hip_bfloat16* const AsP[2] = {smem, smem + BM * BK};
    __hip_bfloat16* const BsP[2] = {smem + 2 * BM * BK, smem + 3 * BM * BK};

    const int tid  = threadIdx.x;
    const int wave = tid >> 6;
    const int lane = tid & 63;

    const int bid = blockIdx.x;
    const int xcd = bid & 7;
    const int jb  = bid >> 3;
    const int bm  = xcd * 16 + (jb >> 2);
    const int bn  = jb & 3;

    const int wm = (wave >> 1) * 64;
    const int wn = (wave & 1) * 64;

    const int srow = lane >> 3;
    const int scol = ((lane & 7) ^ srow) * 8;

    const float* Agf = Agf0 + (size_t)(bm * BM) * K;
    const __hip_bfloat16* Bg = Bt + (size_t)(bn * BN) * K;

    f32x4 acc[4][4] = {};
    float4 va[4][2];

#define STAGE_B0(buf, k0)                                                                            \
    do {                                                                                             \
        _Pragma("unroll") for (int jj = 0; jj < 4; ++jj) {                                           \
            const int rbase = (jj * 4 + wave) * 8;                                                   \
            __builtin_amdgcn_global_load_lds(                                                        \
                (const __attribute__((address_space(1))) void*)(Bg + (size_t)(rbase + srow) * K + (k0) + scol), \
                (__attribute__((address_space(3))) void*)(&BsP[buf][rbase * BK]), 16, 0, 0);         \
        }                                                                                            \
    } while (0)

#define LOAD_A0(k0)                                                                                  \
    do {                                                                                             \
        _Pragma("unroll") for (int jj = 0; jj < 4; ++jj) {                                           \
            const int rbase = (jj * 4 + wave) * 8;                                                   \
            const float* s = Agf + (size_t)(rbase + srow) * K + (k0) + scol;                         \
            va[jj][0] = *(const float4*)s;                                                           \
            va[jj][1] = *(const float4*)(s + 4);                                                     \
        }                                                                                            \
    } while (0)

#define WRITE_A0(buf)                                                                                \
    do {                                                                                             \
        _Pragma("unroll") for (int jj = 0; jj < 4; ++jj) {                                           \
            const int rbase = (jj * 4 + wave) * 8;                                                   \
            bf16x8 pk;                                                                               \
            _Pragma("unroll") for (int q = 0; q < 4; ++q) {                                          \
                __hip_bfloat16 t0 = __float2bfloat16(((const float*)&va[jj][0])[q]);                 \
                __hip_bfloat16 t1 = __float2bfloat16(((const float*)&va[jj][1])[q]);                 \
                pk[q]     = *(const short*)&t0;                                                      \
                pk[q + 4] = *(const short*)&t1;                                                      \
            }                                                                                        \
            *(bf16x8*)(&AsP[buf][(rbase + srow) * BK + (lane & 7) * 8]) = pk;                        \
        }                                                                                            \
    } while (0)

#define COMPUTE0(buf)                                                                                \
    do {                                                                                             \
        bf16x8 af[4][2], bv[4][2];                                                                   \
        const int fr = lane & 15;                                                                    \
        const int kq = lane >> 4;                                                                    \
        _Pragma("unroll") for (int mi = 0; mi < 4; ++mi) {                                           \
            const int r = wm + mi * 16 + fr;                                                         \
            _Pragma("unroll") for (int kh = 0; kh < 2; ++kh) {                                       \
                const int c = ((kh * 4 + kq) ^ (fr & 7)) * 8;                                        \
                af[mi][kh] = *(const bf16x8*)(&AsP[buf][r * BK + c]);                                \
            }                                                                                        \
        }                                                                                            \
        _Pragma("unroll") for (int ni = 0; ni < 4; ++ni) {                                           \
            const int r = wn + ni * 16 + fr;                                                         \
            _Pragma("unroll") for (int kh = 0; kh < 2; ++kh) {                                       \
                const int c = ((kh * 4 + kq) ^ (fr & 7)) * 8;                                        \
                bv[ni][kh] = *(const bf16x8*)(&BsP[buf][r * BK + c]);                                \
            }                                                                                        \
        }                                                                                            \
        _Pragma("unroll") for (int kh = 0; kh < 2; ++kh)                                             \
            _Pragma("unroll") for (int mi = 0; mi < 4; ++mi)                                         \
                _Pragma("unroll") for (int ni = 0; ni < 4; ++ni)                                     \
                    acc[mi][ni] = __builtin_amdgcn_mfma_f32_16x16x32_bf16(af[mi][kh], bv[ni][kh],    \
                                                                          acc[mi][ni], 0, 0, 0);    \
    } while (0)

    LOAD_A0(0);
    STAGE_B0(0, 0);
    WRITE_A0(0);
    __syncthreads();
    int cur = 0;
#pragma unroll
    for (int kt = 1; kt < NT; ++kt) {
        LOAD_A0(kt * BK);
        STAGE_B0(cur ^ 1, kt * BK);
        COMPUTE0(cur);
        WRITE_A0(cur ^ 1);
        __syncthreads();
        cur ^= 1;
    }
    COMPUTE0(cur);
    __syncthreads();

    {
        __hip_bfloat16* S = smem + wave * (64 * EP);
        const int cfr = lane & 15;
        const int cfq = lane >> 4;
        float bs[4];
#pragma unroll
        for (int ni = 0; ni < 4; ++ni) bs[ni] = bias[bn * BN + wn + ni * 16 + cfr];
#pragma unroll
        for (int mi = 0; mi < 4; ++mi)
#pragma unroll
            for (int ni = 0; ni < 4; ++ni)
#pragma unroll
                for (int r = 0; r < 4; ++r)
                    S[(mi * 16 + cfq * 4 + r) * EP + ni * 16 + cfr] =
                        __float2bfloat16(acc[mi][ni][r] + bs[ni]);
        const int rq = lane >> 3;
        const int cl = (lane & 7) * 8;
#pragma unroll
        for (int p = 0; p < 8; ++p) {
            const int lr = p * 8 + rq;
            bf16x8 v = *(const bf16x8*)(S + lr * EP + cl);
            *(bf16x8*)(&Cb[(size_t)(bm * BM + wm + lr) * N + bn * BN + wn + cl]) = v;
        }
    }
#undef STAGE_B0
#undef LOAD_A0
#undef WRITE_A0
#undef COMPUTE0
}

// ---------------- ring-3 GEMM (layers 1-3): Cb = bf16(A * Bt^T + bias) ------
// 128x64 tile, 4 waves (2M x 2N, each 64x32), BK=64, ring-3 LDS (72KB dyn ->
// 2 blocks/CU), counted vmcnt(6): loads stay 2 K-tiles in flight across raw
// s_barriers, ONE barrier per K-tile. Chunk-XOR swizzle, XCD swizzle.
//
// Safety: COMPUTE(t) reads slot t%3 (loads issued iter t-2, retired by the
// vmcnt at the t-1 boundary, barrier-published). STAGE(t+2) writes slot
// (t-1)%3, which all waves finished reading before the last barrier.
__global__ __launch_bounds__(256) void gemm_r3(const __hip_bfloat16* __restrict__ A,
                                               const __hip_bfloat16* __restrict__ Bt,
                                               const float* __restrict__ bias,
                                               __hip_bfloat16* __restrict__ Cb) {
    constexpr int K = D;
    constexpr int N = D;
    extern __shared__ __hip_bfloat16 smem[];

    const int tid  = threadIdx.x;
    const int wave = tid >> 6;
    const int lane = tid & 63;

    // XCD swizzle: 1024 blocks = 8 XCDs x (16 bm x 8 bn); per XCD: 16 A-panels
    // (2MB) + full B (0.5MB) resident in its 4MB L2.
    const int bid = blockIdx.x;
    const int xcd = bid & 7;
    const int jb  = bid >> 3;            // 0..127
    const int bm  = xcd * 16 + (jb >> 3); // 0..127
    const int bn  = jb & 7;               // 0..7

    const int wm = (wave >> 1) * 64; // {0,64}
    const int wn = (wave & 1) * 32;  // {0,32}

    const int srow = lane >> 3;
    const int scol = ((lane & 7) ^ srow) * 8;

    const __hip_bfloat16* Ag = A  + (size_t)(bm * RBM) * K;
    const __hip_bfloat16* Bg = Bt + (size_t)(bn * RBN) * K;

    f32x4 acc[4][2] = {};

#define STAGE(slot, k0)                                                                              \
    do {                                                                                             \
        __hip_bfloat16* const Asl = smem + (slot) * RSLOT;                                           \
        __hip_bfloat16* const Bsl = Asl + RBM * BK;                                                  \
        _Pragma("unroll") for (int jj = 0; jj < 4; ++jj) {                                           \
            const int rbase = (wave * 4 + jj) * 8;                                                   \
            __builtin_amdgcn_global_load_lds(                                                        \
                (const __attribute__((address_space(1))) void*)(Ag + (size_t)(rbase + srow) * K + (k0) + scol), \
                (__attribute__((address_space(3))) void*)(Asl + rbase * BK), 16, 0, 0);              \
        }                                                                                            \
        _Pragma("unroll") for (int jj = 0; jj < 2; ++jj) {                                           \
            const int rbase = (wave * 2 + jj) * 8;                                                   \
            __builtin_amdgcn_global_load_lds(                                                        \
                (const __attribute__((address_space(1))) void*)(Bg + (size_t)(rbase + srow) * K + (k0) + scol), \
                (__attribute__((address_space(3))) void*)(Bsl + rbase * BK), 16, 0, 0);              \
        }                                                                                            \
    } while (0)

#define COMPUTE(slot)                                                                                \
    do {                                                                                             \
        const __hip_bfloat16* const Asl = smem + (slot) * RSLOT;                                     \
        const __hip_bfloat16* const Bsl = Asl + RBM * BK;                                            \
        bf16x8 af[4][2], bv[2][2];                                                                   \
        const int fr = lane & 15;                                                                    \
        const int kq = lane >> 4;                                                                    \
        _Pragma("unroll") for (int mi = 0; mi < 4; ++mi) {                                           \
            const int r = wm + mi * 16 + fr;                                                         \
            _Pragma("unroll") for (int kh = 0; kh < 2; ++kh) {                                       \
                const int c = ((kh * 4 + kq) ^ (fr & 7)) * 8;                                        \
                af[mi][kh] = *(const bf16x8*)(&Asl[r * BK + c]);                                     \
            }                                                                                        \
        }                                                                                            \
        _Pragma("unroll") for (int ni = 0; ni < 2; ++ni) {                                           \
            const int r = wn + ni * 16 + fr;                                                         \
            _Pragma("unroll") for (int kh = 0; kh < 2; ++kh) {                                       \
                const int c = ((kh * 4 + kq) ^ (fr & 7)) * 8;                                        \
                bv[ni][kh] = *(const bf16x8*)(&Bsl[r * BK + c]);                                     \
            }                                                                                        \
        }                                                                                            \
        _Pragma("unroll") for (int kh = 0; kh < 2; ++kh)                                             \
            _Pragma("unroll") for (int mi = 0; mi < 4; ++mi)                                         \
                _Pragma("unroll") for (int ni = 0; ni < 2; ++ni)                                     \
                    acc[mi][ni] = __builtin_amdgcn_mfma_f32_16x16x32_bf16(af[mi][kh], bv[ni][kh],    \
                                                                          acc[mi][ni], 0, 0, 0);    \
    } while (0)

    // prologue: tiles 0,1 in flight; wait own tile-0 loads; publish block-wide
    STAGE(0, 0);
    STAGE(1, BK);
    VMCNT(6);
    SBAR();

#pragma unroll
    for (int t = 0; t < NT; ++t) {
        if (t + 2 < NT) STAGE((t + 2) % 3, (t + 2) * BK); // slot (t-1)%3: freed before last barrier
        COMPUTE(t % 3);
        if (t < NT - 1) {
            if (t + 2 < NT) {
                VMCNT(6); // retire tile t+1's 6 loads; keep tile t+2's 6 in flight
            } else {
                VMCNT(0); // tail drain
            }
            SBAR(); // tile t+1 published block-wide
        }
    }
    __syncthreads(); // epilogue reuses LDS (first 20KB, disjoint from slot 1 anyway)

    // ---- epilogue: stage wave's 64x32 tile in LDS, store coalesced 64B rows --
    // C/D layout: col=lane&15, row=(lane>>4)*4 + r  [m89-verified]
    {
        __hip_bfloat16* S = smem + wave * (64 * REP);
        const int cfr = lane & 15;
        const int cfq = lane >> 4;
        float bs[2];
#pragma unroll
        for (int ni = 0; ni < 2; ++ni) bs[ni] = bias[bn * RBN + wn + ni * 16 + cfr];
#pragma unroll
        for (int mi = 0; mi < 4; ++mi)
#pragma unroll
            for (int ni = 0; ni < 2; ++ni)
#pragma unroll
                for (int r = 0; r < 4; ++r)
                    S[(mi * 16 + cfq * 4 + r) * REP + ni * 16 + cfr] =
                        __float2bfloat16(acc[mi][ni][r] + bs[ni]);
        const int rq = lane >> 2;      // 0..15
        const int cl = (lane & 3) * 8; // 0,8,16,24
#pragma unroll
        for (int p = 0; p < 4; ++p) {
            const int lr = p * 16 + rq;
            bf16x8 v = *(const bf16x8*)(S + lr * REP + cl);
            *(bf16x8*)(&Cb[(size_t)(bm * RBM + wm + lr) * N + bn * RBN + wn + cl]) = v;
        }
    }
#undef STAGE
#undef COMPUTE
}

// ---------------- fused parallel scan: h_t = max(0, a_t + u*h_{t-1}) ---------
// Chunk decomposition (h>=0 domain): F_c(h) = max(m, d + e*h), e = u^CH.
template <int MODE>
__global__ __launch_bounds__(512) void scan_k(const __hip_bfloat16* __restrict__ xh,
                                              const float* __restrict__ u,
                                              float* __restrict__ outf,
                                              __hip_bfloat16* __restrict__ outb) {
    __shared__ float4 md[NCH][32];
    const int i2  = threadIdx.x & 31;
    const int c   = threadIdx.x >> 5; // 0..15
    const int idx = blockIdx.x * 64 + i2 * 2;
    const float u0 = u[idx & (D - 1)];
    const float u1 = u[(idx + 1) & (D - 1)];

    const __hip_bfloat16* p = xh + (size_t)c * CH * M_TOT + idx;
    unsigned int xv[CH];
#pragma unroll
    for (int t = 0; t < CH; ++t) xv[t] = *(const unsigned int*)(p + (size_t)t * M_TOT);

    float m0 = 0.f, d0 = 0.f, m1 = 0.f, d1 = 0.f;
#pragma unroll
    for (int t = 0; t < CH; ++t) {
        const float a0 = __uint_as_float(xv[t] << 16);
        const float a1 = __uint_as_float(xv[t] & 0xffff0000u);
        m0 = fmaxf(fmaf(u0, m0, a0), 0.f);
        d0 = fmaf(u0, d0, a0);
        m1 = fmaxf(fmaf(u1, m1, a1), 0.f);
        d1 = fmaf(u1, d1, a1);
    }
    md[c][i2] = make_float4(m0, d0, m1, d1);
    __syncthreads();

    float e0 = u0 * u0, e1 = u1 * u1;       // u^2
    e0 *= e0; e0 *= e0; e0 *= e0; e0 *= e0; // u^32 == u^CH
    e1 *= e1; e1 *= e1; e1 *= e1; e1 *= e1;
    float h0 = 0.f, h1 = 0.f;
    for (int jj = 0; jj < c; ++jj) {
        const float4 v = md[jj][i2];
        h0 = fmaxf(v.x, fmaf(e0, h0, v.y));
        h1 = fmaxf(v.z, fmaf(e1, h1, v.w));
    }

    const size_t base = (size_t)c * CH * M_TOT + idx;
#pragma unroll
    for (int t = 0; t < CH; ++t) {
        const size_t off = base + (size_t)t * M_TOT;
        const float a0 = __uint_as_float(xv[t] << 16);
        const float a1 = __uint_as_float(xv[t] & 0xffff0000u);
        h0 = fmaxf(fmaf(u0, h0, a0), 0.f);
        h1 = fmaxf(fmaf(u1, h1, a1), 0.f);
        if (MODE & 1) *(float2*)(outf + off) = make_float2(h0, h1);
        if (MODE & 2) {
            __hip_bfloat16 b0 = __float2bfloat16(h0);
            __hip_bfloat16 b1 = __float2bfloat16(h1);
            unsigned int pk = (unsigned int)(*(unsigned short*)&b0) |
                              ((unsigned int)(*(unsigned short*)&b1) << 16);
            *(unsigned int*)(outb + off) = pk;
        }
    }
}

extern "C" void kernel_launch(void* const* d_in, const int* in_sizes, int n_in,
                              void* d_out, int out_size, void* d_ws, size_t ws_size,
                              hipStream_t stream) {
    const float* x = (const float*)d_in[0]; // [T, B, Din]
    const float* W = (const float*)d_in[1]; // [L, Dh, Din]
    const float* b = (const float*)d_in[2]; // [L, Dh]
    const float* u = (const float*)d_in[3]; // [L, Dh]
    float* out = (float*)d_out;             // [T, B, Dh]

    __hip_bfloat16* Wb = (__hip_bfloat16*)d_ws;                                       // 2 MB
    __hip_bfloat16* Ab = (__hip_bfloat16*)((char*)d_ws + (size_t)NLAYER * D * D * 2); // 16.8 MB
    __hip_bfloat16* Xh = Ab + (size_t)M_TOT * D;                                      // 16.8 MB

    (void)hipFuncSetAttribute((const void*)gemm_r3,
                              hipFuncAttributeMaxDynamicSharedMemorySize, RSMEM_BYTES);

    convert_k<<<(NLAYER * D * D / 4) / 256, 256, 0, stream>>>(W, Wb);

    for (int l = 0; l < NLAYER; ++l) {
        if (l == 0) {
            gemm_l0<<<(M_TOT / BM) * (D / BN), 256, 0, stream>>>(x, Wb, b, Xh);
        } else {
            gemm_r3<<<(M_TOT / RBM) * (D / RBN), 256, RSMEM_BYTES, stream>>>(
                Ab, Wb + (size_t)l * D * D, b + (size_t)l * D, Xh);
        }
        if (l < NLAYER - 1) {
            scan_k<2><<<M_TOT / 64, 512, 0, stream>>>(Xh, u + (size_t)l * D, nullptr, Ab);
        } else {
            scan_k<1><<<M_TOT / 64, 512, 0, stream>>>(Xh, u + (size_t)l * D, out, nullptr);
        }
    }
}

// Round 9
// 113.602 us; speedup vs baseline: 1.1426x; 1.0230x over previous
//
#include <hip/hip_runtime.h>
#include <hip/hip_bf16.h>

typedef short bf16x8 __attribute__((ext_vector_type(8)));
typedef float f32x4 __attribute__((ext_vector_type(4)));

#define T_LEN 512
#define BATCH 32
#define D 512
#define M_TOT (T_LEN * BATCH) /* 16384 */
#define NLAYER 4

/* ---- layer-0 GEMM (fp32 A, proven round-7 structure) ---- */
#define BM 128
#define BN 128
#define BK 64
#define NT (D / BK) /* 8 K-tiles */
#define EP 72

/* ---- resident-B GEMM (layers 1-3): barrier-free K-loop ---- */
#define QBN 64                     /* output cols per block */
#define QWROWS 32                  /* private M-rows per wave */
#define QBM 256                    /* 8 waves x 32 rows */
#define QB_ELEMS (QBN * D)         /* 32768 elems = 64KB resident B */
#define QA_SLOT (QWROWS * BK)      /* 2048 elems = 4KB per A slot */
#define QSMEM_BYTES ((QB_ELEMS + 8 * 2 * QA_SLOT) * 2) /* 128KB */
#define QEP 72                     /* epilogue stride (32x64 tile) */

#define CH 32            /* scan chunk length */
#define NCH (T_LEN / CH) /* 16 chunks */

#define SBAR()                             \
    do {                                   \
        __builtin_amdgcn_s_barrier();      \
        __builtin_amdgcn_sched_barrier(0); \
    } while (0)
#define VMCNT(n)                                              \
    do {                                                      \
        asm volatile("s_waitcnt vmcnt(" #n ")" ::: "memory"); \
        __builtin_amdgcn_sched_barrier(0);                    \
    } while (0)
#define LGKM0()                                               \
    do {                                                      \
        asm volatile("s_waitcnt lgkmcnt(0)" ::: "memory");    \
        __builtin_amdgcn_sched_barrier(0);                    \
    } while (0)

// ---------------- fp32 -> bf16 convert (W only) ----------------
__global__ __launch_bounds__(256) void convert_k(const float* __restrict__ W,
                                                 __hip_bfloat16* __restrict__ Wb) {
    const int i = (blockIdx.x * 256 + threadIdx.x) * 4; // n = 1048576, exact
    float4 v = *(const float4*)(W + i);
    __hip_bfloat16 h0 = __float2bfloat16(v.x);
    __hip_bfloat16 h1 = __float2bfloat16(v.y);
    __hip_bfloat16 h2 = __float2bfloat16(v.z);
    __hip_bfloat16 h3 = __float2bfloat16(v.w);
    ushort4 o;
    o.x = *(const unsigned short*)&h0;
    o.y = *(const unsigned short*)&h1;
    o.z = *(const unsigned short*)&h2;
    o.w = *(const unsigned short*)&h3;
    *(ushort4*)(Wb + i) = o;
}

// ---------------- layer-0 GEMM: A fp32 (raw x), reg-staged convert ----------
// 128x128 tile, 4 waves, 2-phase dbuf, chunk-XOR swizzle, XCD swizzle,
// LDS-staged coalesced epilogue. Proven round-7 structure, unchanged.
__global__ __launch_bounds__(256) void gemm_l0(const float* __restrict__ Agf0,
                                               const __hip_bfloat16* __restrict__ Bt,
                                               const float* __restrict__ bias,
                                               __hip_bfloat16* __restrict__ Cb) {
    constexpr int K = D;
    constexpr int N = D;
    __shared__ __hip_bfloat16 smem[4 * BM * BK]; // 64KB
    __hip_bfloat16* const AsP[2] = {smem, smem + BM * BK};
    __hip_bfloat16* const BsP[2] = {smem + 2 * BM * BK, smem + 3 * BM * BK};

    const int tid  = threadIdx.x;
    const int wave = tid >> 6;
    const int lane = tid & 63;

    const int bid = blockIdx.x;
    const int xcd = bid & 7;
    const int jb  = bid >> 3;
    const int bm  = xcd * 16 + (jb >> 2);
    const int bn  = jb & 3;

    const int wm = (wave >> 1) * 64;
    const int wn = (wave & 1) * 64;

    const int srow = lane >> 3;
    const int scol = ((lane & 7) ^ srow) * 8;

    const float* Agf = Agf0 + (size_t)(bm * BM) * K;
    const __hip_bfloat16* Bg = Bt + (size_t)(bn * BN) * K;

    f32x4 acc[4][4] = {};
    float4 va[4][2];

#define STAGE_B0(buf, k0)                                                                            \
    do {                                                                                             \
        _Pragma("unroll") for (int jj = 0; jj < 4; ++jj) {                                           \
            const int rbase = (jj * 4 + wave) * 8;                                                   \
            __builtin_amdgcn_global_load_lds(                                                        \
                (const __attribute__((address_space(1))) void*)(Bg + (size_t)(rbase + srow) * K + (k0) + scol), \
                (__attribute__((address_space(3))) void*)(&BsP[buf][rbase * BK]), 16, 0, 0);         \
        }                                                                                            \
    } while (0)

#define LOAD_A0(k0)                                                                                  \
    do {                                                                                             \
        _Pragma("unroll") for (int jj = 0; jj < 4; ++jj) {                                           \
            const int rbase = (jj * 4 + wave) * 8;                                                   \
            const float* s = Agf + (size_t)(rbase + srow) * K + (k0) + scol;                         \
            va[jj][0] = *(const float4*)s;                                                           \
            va[jj][1] = *(const float4*)(s + 4);                                                     \
        }                                                                                            \
    } while (0)

#define WRITE_A0(buf)                                                                                \
    do {                                                                                             \
        _Pragma("unroll") for (int jj = 0; jj < 4; ++jj) {                                           \
            const int rbase = (jj * 4 + wave) * 8;                                                   \
            bf16x8 pk;                                                                               \
            _Pragma("unroll") for (int q = 0; q < 4; ++q) {                                          \
                __hip_bfloat16 t0 = __float2bfloat16(((const float*)&va[jj][0])[q]);                 \
                __hip_bfloat16 t1 = __float2bfloat16(((const float*)&va[jj][1])[q]);                 \
                pk[q]     = *(const short*)&t0;                                                      \
                pk[q + 4] = *(const short*)&t1;                                                      \
            }                                                                                        \
            *(bf16x8*)(&AsP[buf][(rbase + srow) * BK + (lane & 7) * 8]) = pk;                        \
        }                                                                                            \
    } while (0)

#define COMPUTE0(buf)                                                                                \
    do {                                                                                             \
        bf16x8 af[4][2], bv[4][2];                                                                   \
        const int fr = lane & 15;                                                                    \
        const int kq = lane >> 4;                                                                    \
        _Pragma("unroll") for (int mi = 0; mi < 4; ++mi) {                                           \
            const int r = wm + mi * 16 + fr;                                                         \
            _Pragma("unroll") for (int kh = 0; kh < 2; ++kh) {                                       \
                const int c = ((kh * 4 + kq) ^ (fr & 7)) * 8;                                        \
                af[mi][kh] = *(const bf16x8*)(&AsP[buf][r * BK + c]);                                \
            }                                                                                        \
        }                                                                                            \
        _Pragma("unroll") for (int ni = 0; ni < 4; ++ni) {                                           \
            const int r = wn + ni * 16 + fr;                                                         \
            _Pragma("unroll") for (int kh = 0; kh < 2; ++kh) {                                       \
                const int c = ((kh * 4 + kq) ^ (fr & 7)) * 8;                                        \
                bv[ni][kh] = *(const bf16x8*)(&BsP[buf][r * BK + c]);                                \
            }                                                                                        \
        }                                                                                            \
        _Pragma("unroll") for (int kh = 0; kh < 2; ++kh)                                             \
            _Pragma("unroll") for (int mi = 0; mi < 4; ++mi)                                         \
                _Pragma("unroll") for (int ni = 0; ni < 4; ++ni)                                     \
                    acc[mi][ni] = __builtin_amdgcn_mfma_f32_16x16x32_bf16(af[mi][kh], bv[ni][kh],    \
                                                                          acc[mi][ni], 0, 0, 0);    \
    } while (0)

    LOAD_A0(0);
    STAGE_B0(0, 0);
    WRITE_A0(0);
    __syncthreads();
    int cur = 0;
#pragma unroll
    for (int kt = 1; kt < NT; ++kt) {
        LOAD_A0(kt * BK);
        STAGE_B0(cur ^ 1, kt * BK);
        COMPUTE0(cur);
        WRITE_A0(cur ^ 1);
        __syncthreads();
        cur ^= 1;
    }
    COMPUTE0(cur);
    __syncthreads();

    {
        __hip_bfloat16* S = smem + wave * (64 * EP);
        const int cfr = lane & 15;
        const int cfq = lane >> 4;
        float bs[4];
#pragma unroll
        for (int ni = 0; ni < 4; ++ni) bs[ni] = bias[bn * BN + wn + ni * 16 + cfr];
#pragma unroll
        for (int mi = 0; mi < 4; ++mi)
#pragma unroll
            for (int ni = 0; ni < 4; ++ni)
#pragma unroll
                for (int r = 0; r < 4; ++r)
                    S[(mi * 16 + cfq * 4 + r) * EP + ni * 16 + cfr] =
                        __float2bfloat16(acc[mi][ni][r] + bs[ni]);
        const int rq = lane >> 3;
        const int cl = (lane & 7) * 8;
#pragma unroll
        for (int p = 0; p < 8; ++p) {
            const int lr = p * 8 + rq;
            bf16x8 v = *(const bf16x8*)(S + lr * EP + cl);
            *(bf16x8*)(&Cb[(size_t)(bm * BM + wm + lr) * N + bn * BN + wn + cl]) = v;
        }
    }
#undef STAGE_B0
#undef LOAD_A0
#undef WRITE_A0
#undef COMPUTE0
}

// ---------------- resident-B GEMM (layers 1-3) ------------------------------
// Block = 512 thr (8 waves), output tile 256x64. The 64x512 B-panel (64KB,
// chunk-XOR swizzled) is staged ONCE into LDS; each wave owns 32 private
// M-rows with a private double-buffered A-slice (2x4KB). K-loop sync is
// wave-local counted vmcnt (2-deep prefetch) -- ZERO barriers after the
// B prologue. Slot-reuse hazard closed by lgkmcnt(0)+sched_barrier between
// fragment reads and the next stage into the same slot.
__global__ __launch_bounds__(512) void gemm_resB(const __hip_bfloat16* __restrict__ A,
                                                 const __hip_bfloat16* __restrict__ Bt,
                                                 const float* __restrict__ bias,
                                                 __hip_bfloat16* __restrict__ Cb) {
    constexpr int K = D;
    constexpr int N = D;
    extern __shared__ __hip_bfloat16 smem[]; // [64KB B][8 waves x 2 x 4KB A]

    const int tid  = threadIdx.x;
    const int wave = tid >> 6;
    const int lane = tid & 63;

    // XCD swizzle: 512 blocks = 8 XCDs x (8 bm x 8 bn): per XCD the 8
    // A-panels (2MB) + all B (0.5MB) are L2-resident.
    const int bid = blockIdx.x;
    const int xcd = bid & 7;
    const int jb  = bid >> 3;            // 0..63
    const int bm  = xcd * 8 + (jb >> 3); // 0..63
    const int bn  = jb & 7;              // 0..7

    __hip_bfloat16* const Bsm = smem;                                   // 64KB
    __hip_bfloat16* const Awv = smem + QB_ELEMS + wave * (2 * QA_SLOT); // private 8KB

    const int srow = lane >> 3; // 0..7
    const int sch  = lane & 7;  // 0..7

    const __hip_bfloat16* Agw = A + (size_t)(bm * QBM + wave * QWROWS) * K;
    const __hip_bfloat16* Bg  = Bt + (size_t)(bn * QBN) * K;

    f32x4 acc[2][4] = {};

    // ---- prologue: stage resident B (8 loads/wave) + A tiles 0,1 (4+4) ----
#pragma unroll
    for (int p = 0; p < 8; ++p) {
        const int row = p * 8 + wave; // this wave's B rows: row % 8 == wave
        const int sc  = ((lane & ~7) | ((lane & 7) ^ (row & 7))) * 8; // pre-swizzled src col
        __builtin_amdgcn_global_load_lds(
            (const __attribute__((address_space(1))) void*)(Bg + (size_t)row * K + sc),
            (__attribute__((address_space(3))) void*)(Bsm + row * D), 16, 0, 0);
    }
#define STAGE_A(slot, k0)                                                                            \
    do {                                                                                             \
        _Pragma("unroll") for (int jj = 0; jj < 4; ++jj) {                                           \
            const int rbase = jj * 8;                                                                \
            __builtin_amdgcn_global_load_lds(                                                        \
                (const __attribute__((address_space(1))) void*)(Agw + (size_t)(rbase + srow) * K + (k0) + (sch ^ srow) * 8), \
                (__attribute__((address_space(3))) void*)(Awv + (slot) * QA_SLOT + rbase * BK), 16, 0, 0); \
        }                                                                                            \
    } while (0)

    STAGE_A(0, 0);
    STAGE_A(1, BK);
    VMCNT(4); // own B (8) + A0 (4) retired; A1 in flight
    SBAR();   // B published block-wide -- the ONLY barrier

    const int fr = lane & 15;
    const int kq = lane >> 4;

#pragma unroll
    for (int t = 0; t < NT; ++t) {
        if (t > 0) {
            if (t < NT - 1) {
                VMCNT(4); // retire tile t (keep t+1 in flight)
            } else {
                VMCNT(0); // tail
            }
        }
        const __hip_bfloat16* Asl = Awv + (t & 1) * QA_SLOT;
        bf16x8 af[2][2], bv[4][2];
#pragma unroll
        for (int mi = 0; mi < 2; ++mi)
#pragma unroll
            for (int kh = 0; kh < 2; ++kh) {
                const int c = ((kh * 4 + kq) ^ (fr & 7)) * 8;
                af[mi][kh] = *(const bf16x8*)(&Asl[(mi * 16 + fr) * BK + c]);
            }
#pragma unroll
        for (int ni = 0; ni < 4; ++ni)
#pragma unroll
            for (int kh = 0; kh < 2; ++kh) {
                const int n = ni * 16 + fr;
                const int c = t * BK + (((kh * 4 + kq) ^ (fr & 7)) * 8);
                bv[ni][kh] = *(const bf16x8*)(&Bsm[n * D + c]);
            }
        LGKM0(); // reads landed in VGPRs: slot (t&1) free, MFMA ordering pinned
        if (t + 2 < NT) STAGE_A(t & 1, (t + 2) * BK); // wave-private, no barrier
        __builtin_amdgcn_sched_barrier(0);
        __builtin_amdgcn_s_setprio(1);
#pragma unroll
        for (int kh = 0; kh < 2; ++kh)
#pragma unroll
            for (int mi = 0; mi < 2; ++mi)
#pragma unroll
                for (int ni = 0; ni < 4; ++ni)
                    acc[mi][ni] = __builtin_amdgcn_mfma_f32_16x16x32_bf16(af[mi][kh], bv[ni][kh],
                                                                          acc[mi][ni], 0, 0, 0);
        __builtin_amdgcn_s_setprio(0);
    }
#undef STAGE_A

    // ---- epilogue: stage wave's 32x64 tile in its PRIVATE region ----------
    // (wave-local: no barrier needed; compiler orders LDS writes after reads)
    // C/D layout: col=lane&15, row=(lane>>4)*4 + r  [m89-verified]
    {
        __hip_bfloat16* S = Awv; // 32 x QEP = 4.6KB <= 8KB private
        const int cfr = lane & 15;
        const int cfq = lane >> 4;
        float bs[4];
#pragma unroll
        for (int ni = 0; ni < 4; ++ni) bs[ni] = bias[bn * QBN + ni * 16 + cfr];
#pragma unroll
        for (int mi = 0; mi < 2; ++mi)
#pragma unroll
            for (int ni = 0; ni < 4; ++ni)
#pragma unroll
                for (int r = 0; r < 4; ++r)
                    S[(mi * 16 + cfq * 4 + r) * QEP + ni * 16 + cfr] =
                        __float2bfloat16(acc[mi][ni][r] + bs[ni]);
        const int rq = lane >> 3;      // 0..7
        const int cl = (lane & 7) * 8; // 0..56
#pragma unroll
        for (int p = 0; p < 4; ++p) {
            const int lr = p * 8 + rq;
            bf16x8 v = *(const bf16x8*)(S + lr * QEP + cl);
            *(bf16x8*)(&Cb[(size_t)(bm * QBM + wave * QWROWS + lr) * N + bn * QBN + cl]) = v;
        }
    }
}

// ---------------- fused parallel scan: h_t = max(0, a_t + u*h_{t-1}) ---------
// Chunk decomposition (h>=0 domain): F_c(h) = max(m, d + e*h), e = u^CH.
template <int MODE>
__global__ __launch_bounds__(512) void scan_k(const __hip_bfloat16* __restrict__ xh,
                                              const float* __restrict__ u,
                                              float* __restrict__ outf,
                                              __hip_bfloat16* __restrict__ outb) {
    __shared__ float4 md[NCH][32];
    const int i2  = threadIdx.x & 31;
    const int c   = threadIdx.x >> 5; // 0..15
    const int idx = blockIdx.x * 64 + i2 * 2;
    const float u0 = u[idx & (D - 1)];
    const float u1 = u[(idx + 1) & (D - 1)];

    const __hip_bfloat16* p = xh + (size_t)c * CH * M_TOT + idx;
    unsigned int xv[CH];
#pragma unroll
    for (int t = 0; t < CH; ++t) xv[t] = *(const unsigned int*)(p + (size_t)t * M_TOT);

    float m0 = 0.f, d0 = 0.f, m1 = 0.f, d1 = 0.f;
#pragma unroll
    for (int t = 0; t < CH; ++t) {
        const float a0 = __uint_as_float(xv[t] << 16);
        const float a1 = __uint_as_float(xv[t] & 0xffff0000u);
        m0 = fmaxf(fmaf(u0, m0, a0), 0.f);
        d0 = fmaf(u0, d0, a0);
        m1 = fmaxf(fmaf(u1, m1, a1), 0.f);
        d1 = fmaf(u1, d1, a1);
    }
    md[c][i2] = make_float4(m0, d0, m1, d1);
    __syncthreads();

    float e0 = u0 * u0, e1 = u1 * u1;       // u^2
    e0 *= e0; e0 *= e0; e0 *= e0; e0 *= e0; // u^32 == u^CH
    e1 *= e1; e1 *= e1; e1 *= e1; e1 *= e1;
    float h0 = 0.f, h1 = 0.f;
    for (int jj = 0; jj < c; ++jj) {
        const float4 v = md[jj][i2];
        h0 = fmaxf(v.x, fmaf(e0, h0, v.y));
        h1 = fmaxf(v.z, fmaf(e1, h1, v.w));
    }

    const size_t base = (size_t)c * CH * M_TOT + idx;
#pragma unroll
    for (int t = 0; t < CH; ++t) {
        const size_t off = base + (size_t)t * M_TOT;
        const float a0 = __uint_as_float(xv[t] << 16);
        const float a1 = __uint_as_float(xv[t] & 0xffff0000u);
        h0 = fmaxf(fmaf(u0, h0, a0), 0.f);
        h1 = fmaxf(fmaf(u1, h1, a1), 0.f);
        if (MODE & 1) *(float2*)(outf + off) = make_float2(h0, h1);
        if (MODE & 2) {
            __hip_bfloat16 b0 = __float2bfloat16(h0);
            __hip_bfloat16 b1 = __float2bfloat16(h1);
            unsigned int pk = (unsigned int)(*(unsigned short*)&b0) |
                              ((unsigned int)(*(unsigned short*)&b1) << 16);
            *(unsigned int*)(outb + off) = pk;
        }
    }
}

extern "C" void kernel_launch(void* const* d_in, const int* in_sizes, int n_in,
                              void* d_out, int out_size, void* d_ws, size_t ws_size,
                              hipStream_t stream) {
    const float* x = (const float*)d_in[0]; // [T, B, Din]
    const float* W = (const float*)d_in[1]; // [L, Dh, Din]
    const float* b = (const float*)d_in[2]; // [L, Dh]
    const float* u = (const float*)d_in[3]; // [L, Dh]
    float* out = (float*)d_out;             // [T, B, Dh]

    __hip_bfloat16* Wb = (__hip_bfloat16*)d_ws;                                       // 2 MB
    __hip_bfloat16* Ab = (__hip_bfloat16*)((char*)d_ws + (size_t)NLAYER * D * D * 2); // 16.8 MB
    __hip_bfloat16* Xh = Ab + (size_t)M_TOT * D;                                      // 16.8 MB

    (void)hipFuncSetAttribute((const void*)gemm_resB,
                              hipFuncAttributeMaxDynamicSharedMemorySize, QSMEM_BYTES);

    convert_k<<<(NLAYER * D * D / 4) / 256, 256, 0, stream>>>(W, Wb);

    for (int l = 0; l < NLAYER; ++l) {
        if (l == 0) {
            gemm_l0<<<(M_TOT / BM) * (D / BN), 256, 0, stream>>>(x, Wb, b, Xh);
        } else {
            gemm_resB<<<(M_TOT / QBM) * (D / QBN), 512, QSMEM_BYTES, stream>>>(
                Ab, Wb + (size_t)l * D * D, b + (size_t)l * D, Xh);
        }
        if (l < NLAYER - 1) {
            scan_k<2><<<M_TOT / 64, 512, 0, stream>>>(Xh, u + (size_t)l * D, nullptr, Ab);
        } else {
            scan_k<1><<<M_TOT / 64, 512, 0, stream>>>(Xh, u + (size_t)l * D, out, nullptr);
        }
    }
}